// Round 1
// baseline (1799.195 us; speedup 1.0000x reference)
//
#include <hip/hip_runtime.h>

#define N_NODES 100000
#define N_EDGES 800000
#define IN_DIM 128
#define HID 64
#define OUT_DIM 7

// ---------------- degree ----------------
__global__ void k_deg_init(float* __restrict__ deg) {
    int i = blockIdx.x * blockDim.x + threadIdx.x;
    if (i < N_NODES) deg[i] = 1.0f;   // self-loop
}

__global__ void k_deg_count(const int* __restrict__ ei, float* __restrict__ deg) {
    int e = blockIdx.x * blockDim.x + threadIdx.x;
    if (e < N_EDGES) {
        int d = ei[N_EDGES + e];
        if ((unsigned)d < N_NODES) atomicAdd(&deg[d], 1.0f);
    }
}

__global__ void k_deg_rsqrt(float* __restrict__ deg) {
    int i = blockIdx.x * blockDim.x + threadIdx.x;
    if (i < N_NODES) deg[i] = rsqrtf(deg[i]);
}

// ---------------- GEMM (F=64) with fused agg-init epilogue ----------------
// C = relu?(X) @ W  [N x K] @ [K x 64]
// Writes H[row][col] = c  and  A[row][col] = c*dinv[row]^2 + bias[col]
// 64x64 block tile, 256 threads, 4x4 register tile per thread.
template<int K, bool RELU_IN>
__global__ __launch_bounds__(256)
void k_gemm64(const float* __restrict__ X, const float* __restrict__ W,
              const float* __restrict__ bias, const float* __restrict__ dinv,
              float* __restrict__ H, float* __restrict__ A) {
    constexpr int KB = 32;
    __shared__ float xs[KB][68];   // x transposed: xs[k][row], pad 68 keeps 16B align
    __shared__ float wsh[KB][64];  // wsh[k][col]

    const int tid = threadIdx.x;
    const int tx = tid & 15;       // col group (4 cols)
    const int ty = tid >> 4;       // row group (4 rows)
    const int r0 = blockIdx.x * 64;

    float c[4][4] = {};

    for (int k0 = 0; k0 < K; k0 += KB) {
        // stage X tile: 64 rows x KB
        #pragma unroll
        for (int i = tid; i < 64 * KB; i += 256) {
            int row = i >> 5;      // i / KB
            int kk  = i & 31;      // i % KB
            int gr  = r0 + row;
            float v = 0.0f;
            if (gr < N_NODES) {
                v = X[(size_t)gr * K + k0 + kk];
                if (RELU_IN) v = fmaxf(v, 0.0f);
            }
            xs[kk][row] = v;
        }
        // stage W tile: KB x 64 (contiguous in global)
        #pragma unroll
        for (int i = tid; i < KB * 64; i += 256) {
            wsh[i >> 6][i & 63] = W[(size_t)(k0 + (i >> 6)) * 64 + (i & 63)];
        }
        __syncthreads();

        #pragma unroll
        for (int k = 0; k < KB; ++k) {
            float4 a4 = *(const float4*)&xs[k][ty << 2];
            float4 b4 = *(const float4*)&wsh[k][tx << 2];
            float av[4] = {a4.x, a4.y, a4.z, a4.w};
            float bv[4] = {b4.x, b4.y, b4.z, b4.w};
            #pragma unroll
            for (int i = 0; i < 4; ++i)
                #pragma unroll
                for (int j = 0; j < 4; ++j)
                    c[i][j] = fmaf(av[i], bv[j], c[i][j]);
        }
        __syncthreads();
    }

    // epilogue
    float4 bb = *(const float4*)&bias[tx << 2];
    #pragma unroll
    for (int i = 0; i < 4; ++i) {
        int row = r0 + (ty << 2) + i;
        if (row < N_NODES) {
            float di = dinv[row];
            float d2 = di * di;
            float4 h = make_float4(c[i][0], c[i][1], c[i][2], c[i][3]);
            *(float4*)&H[(size_t)row * 64 + (tx << 2)] = h;
            float4 av = make_float4(fmaf(h.x, d2, bb.x), fmaf(h.y, d2, bb.y),
                                    fmaf(h.z, d2, bb.z), fmaf(h.w, d2, bb.w));
            *(float4*)&A[(size_t)row * 64 + (tx << 2)] = av;
        }
    }
}

// ---------------- scatter-add (F=64): 16 threads per edge ----------------
__global__ __launch_bounds__(256)
void k_scatter64(const int* __restrict__ ei, const float* __restrict__ dinv,
                 const float* __restrict__ H, float* __restrict__ A) {
    long long tid = (long long)blockIdx.x * blockDim.x + threadIdx.x;
    int e = (int)(tid >> 4);
    int q = (int)(tid & 15);
    if (e >= N_EDGES) return;
    int s = ei[e];
    int d = ei[N_EDGES + e];
    if ((unsigned)s >= N_NODES || (unsigned)d >= N_NODES) return;
    float coef = dinv[s] * dinv[d];
    float4 v = *(const float4*)&H[(size_t)s * 64 + (q << 2)];
    float* ap = &A[(size_t)d * 64 + (q << 2)];
    atomicAdd(ap + 0, v.x * coef);
    atomicAdd(ap + 1, v.y * coef);
    atomicAdd(ap + 2, v.z * coef);
    atomicAdd(ap + 3, v.w * coef);
}

// ---------------- layer 3 GEMM (F=7), thread per row ----------------
__global__ __launch_bounds__(256)
void k_gemm3(const float* __restrict__ X, const float* __restrict__ W,
             const float* __restrict__ bias, const float* __restrict__ dinv,
             float* __restrict__ S, float* __restrict__ Out) {
    int row = blockIdx.x * blockDim.x + threadIdx.x;
    if (row >= N_NODES) return;
    float c[7] = {};
    const float* xr = &X[(size_t)row * 64];
    #pragma unroll
    for (int k0 = 0; k0 < 64; k0 += 4) {
        float4 a4 = *(const float4*)&xr[k0];
        float av[4] = {fmaxf(a4.x, 0.0f), fmaxf(a4.y, 0.0f),
                       fmaxf(a4.z, 0.0f), fmaxf(a4.w, 0.0f)};
        #pragma unroll
        for (int kk = 0; kk < 4; ++kk)
            #pragma unroll
            for (int j = 0; j < 7; ++j)
                c[j] = fmaf(av[kk], W[(size_t)(k0 + kk) * 7 + j], c[j]);  // wave-uniform -> s_load
    }
    float di = dinv[row];
    float d2 = di * di;
    #pragma unroll
    for (int j = 0; j < 7; ++j) {
        S[(size_t)row * 7 + j] = c[j];
        Out[(size_t)row * 7 + j] = fmaf(c[j], d2, bias[j]);
    }
}

// ---------------- scatter-add (F=7): thread per edge ----------------
__global__ __launch_bounds__(256)
void k_scatter7(const int* __restrict__ ei, const float* __restrict__ dinv,
                const float* __restrict__ S, float* __restrict__ Out) {
    int e = blockIdx.x * blockDim.x + threadIdx.x;
    if (e >= N_EDGES) return;
    int s = ei[e];
    int d = ei[N_EDGES + e];
    if ((unsigned)s >= N_NODES || (unsigned)d >= N_NODES) return;
    float coef = dinv[s] * dinv[d];
    #pragma unroll
    for (int j = 0; j < 7; ++j)
        atomicAdd(&Out[(size_t)d * 7 + j], S[(size_t)s * 7 + j] * coef);
}

extern "C" void kernel_launch(void* const* d_in, const int* in_sizes, int n_in,
                              void* d_out, int out_size, void* d_ws, size_t ws_size,
                              hipStream_t stream) {
    const float* x  = (const float*)d_in[0];
    const int*   ei = (const int*)d_in[1];
    const float* W1 = (const float*)d_in[2];
    const float* b1 = (const float*)d_in[3];
    const float* W2 = (const float*)d_in[4];
    const float* b2 = (const float*)d_in[5];
    const float* W3 = (const float*)d_in[6];
    const float* b3 = (const float*)d_in[7];
    float* out = (float*)d_out;

    float* wsf  = (float*)d_ws;
    float* dinv = wsf;                                   // N
    float* bufH = wsf + N_NODES;                         // N*64
    float* bufA = bufH + (size_t)N_NODES * 64;           // N*64
    float* bufS = bufA + (size_t)N_NODES * 64;           // N*7

    const int nb_nodes = (N_NODES + 255) / 256;
    const int nb_edges = (N_EDGES + 255) / 256;
    const int nb_gemm  = (N_NODES + 63) / 64;
    const int nb_scat  = (N_EDGES * 16 + 255) / 256;

    // degree / dinv
    k_deg_init<<<nb_nodes, 256, 0, stream>>>(dinv);
    k_deg_count<<<nb_edges, 256, 0, stream>>>(ei, dinv);
    k_deg_rsqrt<<<nb_nodes, 256, 0, stream>>>(dinv);

    // layer 1
    k_gemm64<IN_DIM, false><<<nb_gemm, 256, 0, stream>>>(x, W1, b1, dinv, bufH, bufA);
    k_scatter64<<<nb_scat, 256, 0, stream>>>(ei, dinv, bufH, bufA);

    // layer 2 (in-place: reads bufA with relu, re-inits bufA in epilogue)
    k_gemm64<HID, true><<<nb_gemm, 256, 0, stream>>>(bufA, W2, b2, dinv, bufH, bufA);
    k_scatter64<<<nb_scat, 256, 0, stream>>>(ei, dinv, bufH, bufA);

    // layer 3 (relu on input inside k_gemm3)
    k_gemm3<<<nb_nodes, 256, 0, stream>>>(bufA, W3, b3, dinv, bufS, out);
    k_scatter7<<<nb_edges, 256, 0, stream>>>(ei, dinv, bufS, out);
}

// Round 2
// 394.450 us; speedup vs baseline: 4.5613x; 4.5613x over previous
//
#include <hip/hip_runtime.h>

#define N_NODES 100000
#define N_EDGES 800000
#define IN_DIM 128
#define HID 64
#define OUT_DIM 7
#define NB_SCAN ((N_NODES + 255) / 256)   // 391

// ---------------- CSR build ----------------
__global__ void k_count_init(int* __restrict__ counts) {
    int i = blockIdx.x * blockDim.x + threadIdx.x;
    if (i < N_NODES) counts[i] = 0;
}

__global__ void k_count(const int* __restrict__ ei, int* __restrict__ counts) {
    int e = blockIdx.x * blockDim.x + threadIdx.x;
    if (e < N_EDGES) {
        int d = ei[N_EDGES + e];
        if ((unsigned)d < N_NODES) atomicAdd(&counts[d], 1);
    }
}

// per-block exclusive scan of counts -> row_start (local), block sums -> partials
__global__ __launch_bounds__(256)
void k_scan1(const int* __restrict__ counts, int* __restrict__ row_start,
             int* __restrict__ partials) {
    __shared__ int sm[256];
    int t = threadIdx.x;
    int i = blockIdx.x * 256 + t;
    int v = (i < N_NODES) ? counts[i] : 0;
    sm[t] = v;
    __syncthreads();
    // Hillis-Steele inclusive scan
    #pragma unroll
    for (int off = 1; off < 256; off <<= 1) {
        int add = (t >= off) ? sm[t - off] : 0;
        __syncthreads();
        sm[t] += add;
        __syncthreads();
    }
    if (i < N_NODES) row_start[i] = sm[t] - v;   // exclusive
    if (t == 255) partials[blockIdx.x] = sm[255];
}

// single-block inclusive->exclusive scan of partials (NB_SCAN <= 512)
__global__ __launch_bounds__(512)
void k_scan2(int* __restrict__ partials) {
    __shared__ int sm[512];
    int t = threadIdx.x;
    int v = (t < NB_SCAN) ? partials[t] : 0;
    sm[t] = v;
    __syncthreads();
    #pragma unroll
    for (int off = 1; off < 512; off <<= 1) {
        int add = (t >= off) ? sm[t - off] : 0;
        __syncthreads();
        sm[t] += add;
        __syncthreads();
    }
    if (t < NB_SCAN) partials[t] = sm[t] - v;    // exclusive
}

// add block offsets, init cursors, compute dinv; thread 0 caps row_start[N]
__global__ __launch_bounds__(256)
void k_scan3(const int* __restrict__ counts, int* __restrict__ row_start,
             int* __restrict__ row_cur, const int* __restrict__ partials,
             float* __restrict__ dinv) {
    int i = blockIdx.x * 256 + threadIdx.x;
    if (i < N_NODES) {
        int rs = row_start[i] + partials[blockIdx.x];
        row_start[i] = rs;
        row_cur[i] = rs;
        dinv[i] = rsqrtf((float)counts[i] + 1.0f);
    }
    if (i == 0) row_start[N_NODES] = N_EDGES;
}

__global__ void k_fill(const int* __restrict__ ei, int* __restrict__ row_cur,
                       int* __restrict__ csr_src) {
    int e = blockIdx.x * blockDim.x + threadIdx.x;
    if (e < N_EDGES) {
        int s = ei[e];
        int d = ei[N_EDGES + e];
        if ((unsigned)s < N_NODES && (unsigned)d < N_NODES) {
            int pos = atomicAdd(&row_cur[d], 1);
            csr_src[pos] = s;
        }
    }
}

// ---------------- GEMM (F=64) with fused agg-base epilogue ----------------
// H[row] = relu?(X[row]) @ W ; A[row] = H[row]*dinv^2 + bias
template<int K, bool RELU_IN>
__global__ __launch_bounds__(256)
void k_gemm64(const float* __restrict__ X, const float* __restrict__ W,
              const float* __restrict__ bias, const float* __restrict__ dinv,
              float* __restrict__ H, float* __restrict__ A) {
    constexpr int KB = 32;
    __shared__ float xs[KB][68];
    __shared__ float wsh[KB][64];

    const int tid = threadIdx.x;
    const int tx = tid & 15;
    const int ty = tid >> 4;
    const int r0 = blockIdx.x * 64;

    float c[4][4] = {};

    for (int k0 = 0; k0 < K; k0 += KB) {
        #pragma unroll
        for (int i = tid; i < 64 * KB; i += 256) {
            int row = i >> 5;
            int kk  = i & 31;
            int gr  = r0 + row;
            float v = 0.0f;
            if (gr < N_NODES) {
                v = X[(size_t)gr * K + k0 + kk];
                if (RELU_IN) v = fmaxf(v, 0.0f);
            }
            xs[kk][row] = v;
        }
        #pragma unroll
        for (int i = tid; i < KB * 64; i += 256) {
            wsh[i >> 6][i & 63] = W[(size_t)(k0 + (i >> 6)) * 64 + (i & 63)];
        }
        __syncthreads();

        #pragma unroll
        for (int k = 0; k < KB; ++k) {
            float4 a4 = *(const float4*)&xs[k][ty << 2];
            float4 b4 = *(const float4*)&wsh[k][tx << 2];
            float av[4] = {a4.x, a4.y, a4.z, a4.w};
            float bv[4] = {b4.x, b4.y, b4.z, b4.w};
            #pragma unroll
            for (int i = 0; i < 4; ++i)
                #pragma unroll
                for (int j = 0; j < 4; ++j)
                    c[i][j] = fmaf(av[i], bv[j], c[i][j]);
        }
        __syncthreads();
    }

    float4 bb = *(const float4*)&bias[tx << 2];
    #pragma unroll
    for (int i = 0; i < 4; ++i) {
        int row = r0 + (ty << 2) + i;
        if (row < N_NODES) {
            float di = dinv[row];
            float d2 = di * di;
            float4 h = make_float4(c[i][0], c[i][1], c[i][2], c[i][3]);
            *(float4*)&H[(size_t)row * 64 + (tx << 2)] = h;
            float4 av = make_float4(fmaf(h.x, d2, bb.x), fmaf(h.y, d2, bb.y),
                                    fmaf(h.z, d2, bb.z), fmaf(h.w, d2, bb.w));
            *(float4*)&A[(size_t)row * 64 + (tx << 2)] = av;
        }
    }
}

// ---------------- gather-reduce (F=64): 16 lanes per node ----------------
__global__ __launch_bounds__(256)
void k_gather64(const int* __restrict__ row_start, const int* __restrict__ csr_src,
                const float* __restrict__ dinv, const float* __restrict__ H,
                float* __restrict__ A) {
    int node = blockIdx.x * 16 + (threadIdx.x >> 4);
    int q = threadIdx.x & 15;
    if (node >= N_NODES) return;
    int beg = row_start[node];
    int end = row_start[node + 1];
    float dd = dinv[node];
    float* ap = &A[(size_t)node * 64 + (q << 2)];
    float4 acc = *(const float4*)ap;
    for (int j = beg; j < end; ++j) {
        int s = csr_src[j];
        float coef = dinv[s] * dd;
        float4 v = *(const float4*)&H[(size_t)s * 64 + (q << 2)];
        acc.x = fmaf(v.x, coef, acc.x);
        acc.y = fmaf(v.y, coef, acc.y);
        acc.z = fmaf(v.z, coef, acc.z);
        acc.w = fmaf(v.w, coef, acc.w);
    }
    *(float4*)ap = acc;
}

// ---------------- layer 3 GEMM (F=7), thread per row ----------------
__global__ __launch_bounds__(256)
void k_gemm3(const float* __restrict__ X, const float* __restrict__ W,
             const float* __restrict__ bias, const float* __restrict__ dinv,
             float* __restrict__ S, float* __restrict__ Out) {
    int row = blockIdx.x * blockDim.x + threadIdx.x;
    if (row >= N_NODES) return;
    float c[7] = {};
    const float* xr = &X[(size_t)row * 64];
    #pragma unroll
    for (int k0 = 0; k0 < 64; k0 += 4) {
        float4 a4 = *(const float4*)&xr[k0];
        float av[4] = {fmaxf(a4.x, 0.0f), fmaxf(a4.y, 0.0f),
                       fmaxf(a4.z, 0.0f), fmaxf(a4.w, 0.0f)};
        #pragma unroll
        for (int kk = 0; kk < 4; ++kk)
            #pragma unroll
            for (int j = 0; j < 7; ++j)
                c[j] = fmaf(av[kk], W[(size_t)(k0 + kk) * 7 + j], c[j]);
    }
    float di = dinv[row];
    float d2 = di * di;
    #pragma unroll
    for (int j = 0; j < 7; ++j) {
        S[(size_t)row * 7 + j] = c[j];
        Out[(size_t)row * 7 + j] = fmaf(c[j], d2, bias[j]);
    }
}

// ---------------- gather-reduce (F=7): 8 lanes per node ----------------
__global__ __launch_bounds__(256)
void k_gather7(const int* __restrict__ row_start, const int* __restrict__ csr_src,
               const float* __restrict__ dinv, const float* __restrict__ S,
               float* __restrict__ Out) {
    int node = blockIdx.x * 32 + (threadIdx.x >> 3);
    int j7 = threadIdx.x & 7;
    if (node >= N_NODES || j7 >= 7) return;
    int beg = row_start[node];
    int end = row_start[node + 1];
    float dd = dinv[node];
    float acc = Out[(size_t)node * 7 + j7];
    for (int j = beg; j < end; ++j) {
        int s = csr_src[j];
        acc = fmaf(S[(size_t)s * 7 + j7], dinv[s] * dd, acc);
    }
    Out[(size_t)node * 7 + j7] = acc;
}

extern "C" void kernel_launch(void* const* d_in, const int* in_sizes, int n_in,
                              void* d_out, int out_size, void* d_ws, size_t ws_size,
                              hipStream_t stream) {
    const float* x  = (const float*)d_in[0];
    const int*   ei = (const int*)d_in[1];
    const float* W1 = (const float*)d_in[2];
    const float* b1 = (const float*)d_in[3];
    const float* W2 = (const float*)d_in[4];
    const float* b2 = (const float*)d_in[5];
    const float* W3 = (const float*)d_in[6];
    const float* b3 = (const float*)d_in[7];
    float* out = (float*)d_out;

    char* wsp = (char*)d_ws;
    float* dinv      = (float*)wsp;                       wsp += sizeof(float) * N_NODES;
    int*   counts    = (int*)wsp;                         wsp += sizeof(int) * N_NODES;
    int*   row_start = (int*)wsp;                         wsp += sizeof(int) * (N_NODES + 1);
    int*   row_cur   = (int*)wsp;                         wsp += sizeof(int) * N_NODES;
    int*   partials  = (int*)wsp;                         wsp += sizeof(int) * 512;
    int*   csr_src   = (int*)wsp;                         wsp += sizeof(int) * N_EDGES;
    float* bufH      = (float*)wsp;                       wsp += sizeof(float) * (size_t)N_NODES * 64;
    float* bufA      = (float*)wsp;                       wsp += sizeof(float) * (size_t)N_NODES * 64;
    float* bufS      = (float*)wsp;                       wsp += sizeof(float) * (size_t)N_NODES * 7;

    const int nb_nodes = (N_NODES + 255) / 256;   // 391
    const int nb_edges = (N_EDGES + 255) / 256;
    const int nb_gemm  = (N_NODES + 63) / 64;
    const int nb_g64   = (N_NODES + 15) / 16;
    const int nb_g7    = (N_NODES + 31) / 32;

    // CSR build + dinv
    k_count_init<<<nb_nodes, 256, 0, stream>>>(counts);
    k_count<<<nb_edges, 256, 0, stream>>>(ei, counts);
    k_scan1<<<NB_SCAN, 256, 0, stream>>>(counts, row_start, partials);
    k_scan2<<<1, 512, 0, stream>>>(partials);
    k_scan3<<<NB_SCAN, 256, 0, stream>>>(counts, row_start, row_cur, partials, dinv);
    k_fill<<<nb_edges, 256, 0, stream>>>(ei, row_cur, csr_src);

    // layer 1
    k_gemm64<IN_DIM, false><<<nb_gemm, 256, 0, stream>>>(x, W1, b1, dinv, bufH, bufA);
    k_gather64<<<nb_g64, 256, 0, stream>>>(row_start, csr_src, dinv, bufH, bufA);

    // layer 2 (in-place on bufA input; epilogue rewrites bufA)
    k_gemm64<HID, true><<<nb_gemm, 256, 0, stream>>>(bufA, W2, b2, dinv, bufH, bufA);
    k_gather64<<<nb_g64, 256, 0, stream>>>(row_start, csr_src, dinv, bufH, bufA);

    // layer 3
    k_gemm3<<<nb_nodes, 256, 0, stream>>>(bufA, W3, b3, dinv, bufS, out);
    k_gather7<<<nb_g7, 256, 0, stream>>>(row_start, csr_src, dinv, bufS, out);
}